// Round 1
// baseline (73457.880 us; speedup 1.0000x reference)
//
#include <hip/hip_runtime.h>
#include <hip/hip_bf16.h>

#define HDIM 96
#define G4   384
#define LSEQ 32768
#define BATCH 8

// ---------------------------------------------------------------------------
// Layer 0 scan: one block per batch element, 384 threads (one per gate row).
// W_hh row kept in 96 VGPRs per thread; h broadcast from LDS (float4 reads).
// Input projection is IN=1 -> single FMA per gate.
// Writes h (fp32) for all timesteps to h0buf for the layer-1 input GEMM.
// ---------------------------------------------------------------------------
__global__ __launch_bounds__(384, 1)
void lstm_layer0(const float* __restrict__ x,
                 const float* __restrict__ Wih,   // (384,1)
                 const float* __restrict__ Whh,   // (384,96)
                 const float* __restrict__ bvec,  // (384,)
                 const float* __restrict__ h0,    // (2,96)
                 const float* __restrict__ c0,    // (2,96)
                 float* __restrict__ hout)        // (B,L,96)
{
    const int b = blockIdx.x;
    const int g = threadIdx.x;

    __shared__ __align__(16) float h_sh[HDIM];
    __shared__ float gates_sh[G4];

    float4 w[24];
    const float4* wrow = reinterpret_cast<const float4*>(Whh + g * HDIM);
#pragma unroll
    for (int k = 0; k < 24; ++k) w[k] = wrow[k];

    const float wih  = Wih[g];
    const float bias = bvec[g];
    const bool isTanh = (g >= 2 * HDIM) && (g < 3 * HDIM);

    float c = 0.f;
    if (g < HDIM) { h_sh[g] = h0[g]; c = c0[g]; }
    __syncthreads();

    const float* xb  = x + (size_t)b * LSEQ;
    float*       hob = hout + (size_t)b * LSEQ * HDIM;

    float xt_cur = xb[0];

    for (int t = 0; t < LSEQ; ++t) {
        // prefetch next scalar input (hides load latency behind the step body)
        float xt_next = (t + 1 < LSEQ) ? xb[t + 1] : 0.f;

        float acc = fmaf(wih, xt_cur, bias);
        const float4* h4 = reinterpret_cast<const float4*>(h_sh);
#pragma unroll
        for (int k = 0; k < 24; ++k) {
            float4 hv = h4[k];
            acc = fmaf(w[k].x, hv.x, acc);
            acc = fmaf(w[k].y, hv.y, acc);
            acc = fmaf(w[k].z, hv.z, acc);
            acc = fmaf(w[k].w, hv.w, acc);
        }
        // apply this gate's nonlinearity here (spreads transcendental work
        // over all 6 waves instead of the 1.5 update waves)
        {
            float arg = isTanh ? (-2.f * acc) : (-acc);
            float e = __expf(arg);
            float r = 1.f / (1.f + e);
            gates_sh[g] = isTanh ? (2.f * r - 1.f) : r;
        }
        __syncthreads();

        if (g < HDIM) {
            float ig = gates_sh[g];
            float fg = gates_sh[HDIM + g];
            float gg = gates_sh[2 * HDIM + g];
            float og = gates_sh[3 * HDIM + g];
            c = fg * c + ig * gg;
            float e2 = __expf(-2.f * c);
            float th = 2.f / (1.f + e2) - 1.f;
            float hnew = og * th;
            h_sh[g] = hnew;
            hob[(size_t)t * HDIM + g] = hnew;
        }
        __syncthreads();
        xt_cur = xt_next;
    }
}

// ---------------------------------------------------------------------------
// Layer-1 input projection GEMM (parallel over timesteps):
// xp[b][t][g] = b1[g] + sum_j Wih1[g][j] * h0buf[b][t][j]
// One block = 32 timesteps of one batch; W row in VGPRs, h tile in LDS.
// ---------------------------------------------------------------------------
__global__ __launch_bounds__(384, 1)
void xp_gemm(const float* __restrict__ hin,   // (B,L,96)
             const float* __restrict__ Wih,   // (384,96)
             const float* __restrict__ bvec,  // (384,)
             float* __restrict__ xp,          // (B,T,384) chunk
             int t0, int T)
{
    const int TT = 32;
    const int ntb = T / TT;
    const int b  = blockIdx.x / ntb;
    const int tb = blockIdx.x % ntb;
    const int g  = threadIdx.x;

    __shared__ __align__(16) float h_sh[TT * HDIM];

    float4 w[24];
    const float4* wrow = reinterpret_cast<const float4*>(Wih + g * HDIM);
#pragma unroll
    for (int k = 0; k < 24; ++k) w[k] = wrow[k];
    const float bias = bvec[g];

    const float* src = hin + ((size_t)b * LSEQ + t0 + (size_t)tb * TT) * HDIM;
    for (int i = g; i < TT * HDIM; i += G4) h_sh[i] = src[i];
    __syncthreads();

    float* dst = xp + ((size_t)b * T + (size_t)tb * TT) * G4 + g;
    for (int tt = 0; tt < TT; ++tt) {
        const float4* h4 = reinterpret_cast<const float4*>(h_sh + tt * HDIM);
        float acc = bias;
#pragma unroll
        for (int k = 0; k < 24; ++k) {
            float4 hv = h4[k];
            acc = fmaf(w[k].x, hv.x, acc);
            acc = fmaf(w[k].y, hv.y, acc);
            acc = fmaf(w[k].z, hv.z, acc);
            acc = fmaf(w[k].w, hv.w, acc);
        }
        dst[(size_t)tt * G4] = acc;
    }
}

// ---------------------------------------------------------------------------
// Layer 1 scan + fused head. Same structure as layer 0 but the input
// projection comes precomputed from xp (prefetched one step ahead).
// Carry (h,c) persists across chunks via ws.
// ---------------------------------------------------------------------------
__global__ __launch_bounds__(384, 1)
void lstm_layer1(const float* __restrict__ xp,     // (B,T,384) chunk
                 const float* __restrict__ Whh,    // (384,96)
                 const float* __restrict__ h0,     // (2,96)
                 const float* __restrict__ c0,     // (2,96)
                 float* __restrict__ carry,        // (B, 2*96)
                 const float* __restrict__ head_w, // (1,96)
                 const float* __restrict__ head_b, // (1,)
                 float* __restrict__ out,          // (B,L)
                 int chunk, int T)
{
    const int b = blockIdx.x;
    const int g = threadIdx.x;

    __shared__ __align__(16) float h_sh[HDIM];
    __shared__ float gates_sh[G4];

    float4 w[24];
    const float4* wrow = reinterpret_cast<const float4*>(Whh + g * HDIM);
#pragma unroll
    for (int k = 0; k < 24; ++k) w[k] = wrow[k];

    const bool isTanh = (g >= 2 * HDIM) && (g < 3 * HDIM);

    float* cb = carry + b * 2 * HDIM;
    float c = 0.f;
    if (g < HDIM) {
        if (chunk == 0) { h_sh[g] = h0[HDIM + g]; c = c0[HDIM + g]; }
        else            { h_sh[g] = cb[g];        c = cb[HDIM + g]; }
    }
    // head weights for the wave-0 reduction
    const float hwA = (g < 64) ? head_w[g] : 0.f;
    const float hwB = (g < 32) ? head_w[64 + g] : 0.f;
    const float hb  = head_b[0];
    __syncthreads();

    const float* xpb  = xp + ((size_t)b * T) * G4 + g;
    float*       outb = out + (size_t)b * LSEQ + (size_t)chunk * T;

    float xp_cur = xpb[0];

    for (int t = 0; t < T; ++t) {
        float xp_next = (t + 1 < T) ? xpb[(size_t)(t + 1) * G4] : 0.f;

        float acc = xp_cur;
        const float4* h4 = reinterpret_cast<const float4*>(h_sh);
#pragma unroll
        for (int k = 0; k < 24; ++k) {
            float4 hv = h4[k];
            acc = fmaf(w[k].x, hv.x, acc);
            acc = fmaf(w[k].y, hv.y, acc);
            acc = fmaf(w[k].z, hv.z, acc);
            acc = fmaf(w[k].w, hv.w, acc);
        }
        {
            float arg = isTanh ? (-2.f * acc) : (-acc);
            float e = __expf(arg);
            float r = 1.f / (1.f + e);
            gates_sh[g] = isTanh ? (2.f * r - 1.f) : r;
        }
        __syncthreads();

        if (g < HDIM) {
            float ig = gates_sh[g];
            float fg = gates_sh[HDIM + g];
            float gg = gates_sh[2 * HDIM + g];
            float og = gates_sh[3 * HDIM + g];
            c = fg * c + ig * gg;
            float e2 = __expf(-2.f * c);
            float th = 2.f / (1.f + e2) - 1.f;
            float hnew = og * th;
            h_sh[g] = hnew;
        }
        __syncthreads();

        // fused head: wave 0 reduces sum_j h[j]*head_w[j]
        if (g < 64) {
            float s = h_sh[g] * hwA + ((g < 32) ? h_sh[64 + g] * hwB : 0.f);
            s += __shfl_down(s, 32);
            s += __shfl_down(s, 16);
            s += __shfl_down(s, 8);
            s += __shfl_down(s, 4);
            s += __shfl_down(s, 2);
            s += __shfl_down(s, 1);
            if (g == 0) outb[t] = s + hb;
        }
        xp_cur = xp_next;
    }

    if (g < HDIM) { cb[g] = h_sh[g]; cb[HDIM + g] = c; }
}

// ---------------------------------------------------------------------------
extern "C" void kernel_launch(void* const* d_in, const int* in_sizes, int n_in,
                              void* d_out, int out_size, void* d_ws, size_t ws_size,
                              hipStream_t stream)
{
    const float* x     = (const float*)d_in[0];
    const float* Wih0  = (const float*)d_in[1];
    const float* Whh0  = (const float*)d_in[2];
    const float* b0    = (const float*)d_in[3];
    const float* Wih1  = (const float*)d_in[4];
    const float* Whh1  = (const float*)d_in[5];
    const float* b1    = (const float*)d_in[6];
    const float* h0    = (const float*)d_in[7];
    const float* c0    = (const float*)d_in[8];
    const float* headw = (const float*)d_in[9];
    const float* headb = (const float*)d_in[10];
    float* out = (float*)d_out;

    char* ws = (char*)d_ws;
    const size_t h0bytes = (size_t)BATCH * LSEQ * HDIM * sizeof(float); // 100,663,296

    // pick largest chunk T (power of two) whose xp buffer fits the workspace
    int T = 4096;
    while (T > 512 &&
           h0bytes + (size_t)T * BATCH * G4 * sizeof(float) + 4096 * sizeof(float) > ws_size)
        T >>= 1;

    float* h0buf = (float*)ws;
    float* xpbuf = (float*)(ws + h0bytes);
    float* carry = (float*)(ws + h0bytes + (size_t)T * BATCH * G4 * sizeof(float));

    lstm_layer0<<<BATCH, G4, 0, stream>>>(x, Wih0, Whh0, b0, h0, c0, h0buf);

    const int nch = LSEQ / T;
    for (int ch = 0; ch < nch; ++ch) {
        xp_gemm<<<BATCH * (T / 32), G4, 0, stream>>>(h0buf, Wih1, b1, xpbuf, ch * T, T);
        lstm_layer1<<<BATCH, G4, 0, stream>>>(xpbuf, Whh1, h0, c0, carry,
                                              headw, headb, out, ch, T);
    }
}

// Round 2
// 69496.973 us; speedup vs baseline: 1.0570x; 1.0570x over previous
//
#include <hip/hip_runtime.h>
#include <hip/hip_bf16.h>

#define HDIM 96
#define G4   384
#define LSEQ 32768
#define BATCH 8

__device__ __forceinline__ float rdlane(float v, int l) {
    return __uint_as_float(__builtin_amdgcn_readlane(__float_as_uint(v), l));
}
__device__ __forceinline__ float sigm_(float x) { return 1.f / (1.f + __expf(-x)); }
__device__ __forceinline__ float tanh_(float x) { return 2.f / (1.f + __expf(-2.f * x)) - 1.f; }

// ---------------------------------------------------------------------------
// Scan kernels: 192 threads (3 waves), 2 rows/thread.
//   thread e   (e<96):  rows e (i-gate)      and 192+e (g-gate)
//   thread 96+e:        rows 96+e (f-gate)   and 288+e (o-gate); owns c_e
// h broadcast: per wave, lane regs hA=h[lane], hB=h[64+lane] (lane<32),
// then v_readlane -> SGPR -> v_fmac. 4 accumulators break the fma chain.
// ---------------------------------------------------------------------------
__global__ __launch_bounds__(192, 1)
void lstm_layer0(const float* __restrict__ x,
                 const float* __restrict__ Wih,   // (384,1)
                 const float* __restrict__ Whh,   // (384,96)
                 const float* __restrict__ bvec,  // (384,)
                 const float* __restrict__ h0,    // (2,96)
                 const float* __restrict__ c0,    // (2,96)
                 float* __restrict__ hout)        // (B,L,96)
{
    const int b    = blockIdx.x;
    const int tid  = threadIdx.x;
    const int lane = tid & 63;
    const bool isUpd = (tid >= 96);
    const int e    = isUpd ? (tid - 96) : tid;
    const int r0   = tid;        // i-gate (e<96) or f-gate
    const int r1   = tid + 192;  // g-gate (e<96) or o-gate

    __shared__ __align__(16) float h_sh[HDIM];
    __shared__ float p_sh[HDIM];

    float w0[HDIM], w1[HDIM];
    {
        const float4* W0 = reinterpret_cast<const float4*>(Whh + r0 * HDIM);
        const float4* W1 = reinterpret_cast<const float4*>(Whh + r1 * HDIM);
#pragma unroll
        for (int k = 0; k < 24; ++k) {
            float4 a = W0[k]; w0[4*k] = a.x; w0[4*k+1] = a.y; w0[4*k+2] = a.z; w0[4*k+3] = a.w;
            float4 c4 = W1[k]; w1[4*k] = c4.x; w1[4*k+1] = c4.y; w1[4*k+2] = c4.z; w1[4*k+3] = c4.w;
        }
    }
    const float wi0 = Wih[r0], wi1 = Wih[r1];
    const float bb0 = bvec[r0], bb1 = bvec[r1];

    float c = 0.f;
    if (isUpd) c = c0[e];
    if (tid < HDIM) h_sh[tid] = h0[tid];
    __syncthreads();

    float hA = h_sh[lane];
    float hB = (lane < 32) ? h_sh[64 + lane] : 0.f;

    const float* xb  = x + (size_t)b * LSEQ;
    float*       hob = hout + (size_t)b * LSEQ * HDIM;
    float xt = xb[0];

#pragma unroll 1
    for (int t = 0; t < LSEQ; ++t) {
        float xnext = (t + 1 < LSEQ) ? xb[t + 1] : 0.f;

        float a0 = fmaf(wi0, xt, bb0), a0b = 0.f;
        float a1 = fmaf(wi1, xt, bb1), a1b = 0.f;
#pragma unroll
        for (int j = 0; j < 64; j += 2) {
            float hv0 = rdlane(hA, j);
            float hv1 = rdlane(hA, j + 1);
            a0  = fmaf(w0[j],     hv0, a0);
            a1  = fmaf(w1[j],     hv0, a1);
            a0b = fmaf(w0[j + 1], hv1, a0b);
            a1b = fmaf(w1[j + 1], hv1, a1b);
        }
#pragma unroll
        for (int j = 0; j < 32; j += 2) {
            float hv0 = rdlane(hB, j);
            float hv1 = rdlane(hB, j + 1);
            a0  = fmaf(w0[64 + j],     hv0, a0);
            a1  = fmaf(w1[64 + j],     hv0, a1);
            a0b = fmaf(w0[64 + j + 1], hv1, a0b);
            a1b = fmaf(w1[64 + j + 1], hv1, a1b);
        }
        float gA = a0 + a0b;   // i-pre (e<96) or f-pre
        float gB = a1 + a1b;   // g-pre (e<96) or o-pre

        float sf = 0.f, so = 0.f;
        if (!isUpd) {
            p_sh[e] = sigm_(gA) * tanh_(gB);   // sigmoid(i)*tanh(g)
        } else {
            sf = sigm_(gA);
            so = sigm_(gB);
        }
        __syncthreads();

        if (isUpd) {
            c = fmaf(sf, c, p_sh[e]);
            float hn = so * tanh_(c);
            h_sh[e] = hn;
            hob[(size_t)t * HDIM + e] = hn;
        }
        __syncthreads();

        hA = h_sh[lane];
        hB = (lane < 32) ? h_sh[64 + lane] : 0.f;
        xt = xnext;
    }
}

__global__ __launch_bounds__(192, 1)
void lstm_layer1(const float* __restrict__ xp,     // (B,T,384) chunk (bias folded)
                 const float* __restrict__ Whh,    // (384,96)
                 const float* __restrict__ h0,     // (2,96)
                 const float* __restrict__ c0,     // (2,96)
                 float* __restrict__ carry,        // (B, 192)
                 float* __restrict__ h1out,        // (B,T,96) chunk
                 int chunk, int T)
{
    const int b    = blockIdx.x;
    const int tid  = threadIdx.x;
    const int lane = tid & 63;
    const bool isUpd = (tid >= 96);
    const int e    = isUpd ? (tid - 96) : tid;
    const int r0   = tid;
    const int r1   = tid + 192;

    __shared__ __align__(16) float h_sh[HDIM];
    __shared__ float p_sh[HDIM];

    float w0[HDIM], w1[HDIM];
    {
        const float4* W0 = reinterpret_cast<const float4*>(Whh + r0 * HDIM);
        const float4* W1 = reinterpret_cast<const float4*>(Whh + r1 * HDIM);
#pragma unroll
        for (int k = 0; k < 24; ++k) {
            float4 a = W0[k]; w0[4*k] = a.x; w0[4*k+1] = a.y; w0[4*k+2] = a.z; w0[4*k+3] = a.w;
            float4 c4 = W1[k]; w1[4*k] = c4.x; w1[4*k+1] = c4.y; w1[4*k+2] = c4.z; w1[4*k+3] = c4.w;
        }
    }

    float* cb = carry + b * 2 * HDIM;
    float c = 0.f;
    if (isUpd) c = (chunk == 0) ? c0[HDIM + e] : cb[HDIM + e];
    if (tid < HDIM) h_sh[tid] = (chunk == 0) ? h0[HDIM + tid] : cb[tid];
    __syncthreads();

    float hA = h_sh[lane];
    float hB = (lane < 32) ? h_sh[64 + lane] : 0.f;

    const float* xpb = xp + (size_t)b * T * G4;
    float*       hb1 = h1out + (size_t)b * T * HDIM;

    float xc0 = xpb[r0];
    float xc1 = xpb[r1];

#pragma unroll 1
    for (int t = 0; t < T; ++t) {
        float xn0 = 0.f, xn1 = 0.f;
        if (t + 1 < T) {
            const float* nx = xpb + (size_t)(t + 1) * G4;
            xn0 = nx[r0];
            xn1 = nx[r1];
        }

        float a0 = xc0, a0b = 0.f;
        float a1 = xc1, a1b = 0.f;
#pragma unroll
        for (int j = 0; j < 64; j += 2) {
            float hv0 = rdlane(hA, j);
            float hv1 = rdlane(hA, j + 1);
            a0  = fmaf(w0[j],     hv0, a0);
            a1  = fmaf(w1[j],     hv0, a1);
            a0b = fmaf(w0[j + 1], hv1, a0b);
            a1b = fmaf(w1[j + 1], hv1, a1b);
        }
#pragma unroll
        for (int j = 0; j < 32; j += 2) {
            float hv0 = rdlane(hB, j);
            float hv1 = rdlane(hB, j + 1);
            a0  = fmaf(w0[64 + j],     hv0, a0);
            a1  = fmaf(w1[64 + j],     hv0, a1);
            a0b = fmaf(w0[64 + j + 1], hv1, a0b);
            a1b = fmaf(w1[64 + j + 1], hv1, a1b);
        }
        float gA = a0 + a0b;
        float gB = a1 + a1b;

        float sf = 0.f, so = 0.f;
        if (!isUpd) {
            p_sh[e] = sigm_(gA) * tanh_(gB);
        } else {
            sf = sigm_(gA);
            so = sigm_(gB);
        }
        __syncthreads();

        if (isUpd) {
            c = fmaf(sf, c, p_sh[e]);
            float hn = so * tanh_(c);
            h_sh[e] = hn;
            hb1[(size_t)t * HDIM + e] = hn;
        }
        __syncthreads();

        hA = h_sh[lane];
        hB = (lane < 32) ? h_sh[64 + lane] : 0.f;
        xc0 = xn0;
        xc1 = xn1;
    }

    if (isUpd) { cb[e] = h_sh[e]; cb[HDIM + e] = c; }
}

// ---------------------------------------------------------------------------
// Layer-1 input projection GEMM (parallel over timesteps).
// ---------------------------------------------------------------------------
__global__ __launch_bounds__(384, 1)
void xp_gemm(const float* __restrict__ hin,   // (B,L,96)
             const float* __restrict__ Wih,   // (384,96)
             const float* __restrict__ bvec,  // (384,)
             float* __restrict__ xp,          // (B,T,384) chunk
             int t0, int T)
{
    const int TT = 32;
    const int ntb = T / TT;
    const int b  = blockIdx.x / ntb;
    const int tb = blockIdx.x % ntb;
    const int g  = threadIdx.x;

    __shared__ __align__(16) float h_sh[TT * HDIM];

    float4 w[24];
    const float4* wrow = reinterpret_cast<const float4*>(Wih + g * HDIM);
#pragma unroll
    for (int k = 0; k < 24; ++k) w[k] = wrow[k];
    const float bias = bvec[g];

    const float* src = hin + ((size_t)b * LSEQ + t0 + (size_t)tb * TT) * HDIM;
    for (int i = g; i < TT * HDIM; i += G4) h_sh[i] = src[i];
    __syncthreads();

    float* dst = xp + ((size_t)b * T + (size_t)tb * TT) * G4 + g;
    for (int tt = 0; tt < TT; ++tt) {
        const float4* h4 = reinterpret_cast<const float4*>(h_sh + tt * HDIM);
        float acc0 = bias, acc1 = 0.f, acc2 = 0.f, acc3 = 0.f;
#pragma unroll
        for (int k = 0; k < 24; ++k) {
            float4 hv = h4[k];
            acc0 = fmaf(w[k].x, hv.x, acc0);
            acc1 = fmaf(w[k].y, hv.y, acc1);
            acc2 = fmaf(w[k].z, hv.z, acc2);
            acc3 = fmaf(w[k].w, hv.w, acc3);
        }
        dst[(size_t)tt * G4] = (acc0 + acc1) + (acc2 + acc3);
    }
}

// ---------------------------------------------------------------------------
// Head GEMV over one chunk: out[b][t] = h1[b][t][:] . head_w + head_b
// One wave per timestep (4 waves / block).
// ---------------------------------------------------------------------------
__global__ __launch_bounds__(256, 1)
void head_gemv(const float* __restrict__ h1,     // (B,T,96)
               const float* __restrict__ head_w, // (96,)
               const float* __restrict__ head_b, // (1,)
               float* __restrict__ out,          // (B,L)
               int chunk, int T)
{
    const int idx  = blockIdx.x * 4 + (threadIdx.x >> 6);
    const int lane = threadIdx.x & 63;
    const int b = idx / T;
    const int t = idx % T;

    const float* hp = h1 + ((size_t)b * T + t) * HDIM;
    float s = hp[lane] * head_w[lane];
    if (lane < 32) s = fmaf(hp[64 + lane], head_w[64 + lane], s);
    s += __shfl_down(s, 32);
    s += __shfl_down(s, 16);
    s += __shfl_down(s, 8);
    s += __shfl_down(s, 4);
    s += __shfl_down(s, 2);
    s += __shfl_down(s, 1);
    if (lane == 0) out[(size_t)b * LSEQ + (size_t)chunk * T + t] = s + head_b[0];
}

// ---------------------------------------------------------------------------
extern "C" void kernel_launch(void* const* d_in, const int* in_sizes, int n_in,
                              void* d_out, int out_size, void* d_ws, size_t ws_size,
                              hipStream_t stream)
{
    const float* x     = (const float*)d_in[0];
    const float* Wih0  = (const float*)d_in[1];
    const float* Whh0  = (const float*)d_in[2];
    const float* b0    = (const float*)d_in[3];
    const float* Wih1  = (const float*)d_in[4];
    const float* Whh1  = (const float*)d_in[5];
    const float* b1    = (const float*)d_in[6];
    const float* h0    = (const float*)d_in[7];
    const float* c0    = (const float*)d_in[8];
    const float* headw = (const float*)d_in[9];
    const float* headb = (const float*)d_in[10];
    float* out = (float*)d_out;

    char* ws = (char*)d_ws;
    const size_t h0bytes = (size_t)BATCH * LSEQ * HDIM * sizeof(float); // 100.7 MB

    // largest power-of-two chunk T whose buffers fit the workspace
    int T = 4096;
    while (T > 512) {
        size_t need = h0bytes
                    + (size_t)T * BATCH * G4 * sizeof(float)    // xp
                    + (size_t)T * BATCH * HDIM * sizeof(float)  // h1
                    + 8192;
        if (need <= ws_size) break;
        T >>= 1;
    }

    float* h0buf = (float*)ws;
    float* xpbuf = (float*)(ws + h0bytes);
    float* h1buf = (float*)(ws + h0bytes + (size_t)T * BATCH * G4 * sizeof(float));
    float* carry = (float*)(ws + h0bytes + (size_t)T * BATCH * G4 * sizeof(float)
                               + (size_t)T * BATCH * HDIM * sizeof(float));

    lstm_layer0<<<BATCH, 192, 0, stream>>>(x, Wih0, Whh0, b0, h0, c0, h0buf);

    const int nch = LSEQ / T;
    for (int ch = 0; ch < nch; ++ch) {
        xp_gemm<<<BATCH * (T / 32), G4, 0, stream>>>(h0buf, Wih1, b1, xpbuf, ch * T, T);
        lstm_layer1<<<BATCH, 192, 0, stream>>>(xpbuf, Whh1, h0, c0, carry, h1buf, ch, T);
        head_gemv<<<BATCH * T / 4, 256, 0, stream>>>(h1buf, headw, headb, out, ch, T);
    }
}